// Round 4
// baseline (677.413 us; speedup 1.0000x reference)
//
#include <hip/hip_runtime.h>
#include <cmath>

#define B_ 2
#define S_ 2048
#define D_ 1024
#define H_ 16
#define HD_ 64

typedef __attribute__((ext_vector_type(8))) short bf16x8;
typedef __attribute__((ext_vector_type(4))) short bf16x4;
typedef __attribute__((ext_vector_type(4))) float floatx4;
#define MFMA_BF16(a, b, c) __builtin_amdgcn_mfma_f32_16x16x32_bf16(a, b, c, 0, 0, 0)

__device__ __forceinline__ ushort f2bf(float x) {
    union { float f; unsigned u; } v; v.f = x;
    unsigned u = v.u;
    return (ushort)((u + 0x7FFFu + ((u >> 16) & 1u)) >> 16);
}
__device__ __forceinline__ float bf2f(ushort b) {
    union { unsigned u; float f; } v; v.u = ((unsigned)b) << 16;
    return v.f;
}

// async global->LDS, 16B per lane; LDS dest = base + lane*16 (wave-uniform base)
__device__ __forceinline__ void g2l16(const ushort* g, ushort* l) {
    __builtin_amdgcn_global_load_lds(
        (const __attribute__((address_space(1))) unsigned int*)g,
        (__attribute__((address_space(3))) unsigned int*)l, 16, 0, 0);
}

// ---------------------------------------------------------------------------
// fp32 -> (hi, lo) bf16 split, elementwise. n4 = n/4.
// ---------------------------------------------------------------------------
__global__ __launch_bounds__(256) void f32_split_bf16(
    const float* __restrict__ in, ushort* __restrict__ hi,
    ushort* __restrict__ lo, int n4)
{
    int i = blockIdx.x * 256 + threadIdx.x;
    if (i >= n4) return;
    float4 v = ((const float4*)in)[i];
    bf16x4 h, l;
    float vv[4] = {v.x, v.y, v.z, v.w};
#pragma unroll
    for (int j = 0; j < 4; ++j) {
        ushort hb = f2bf(vv[j]);
        h[j] = (short)hb;
        l[j] = (short)f2bf(vv[j] - bf2f(hb));
    }
    ((bf16x4*)hi)[i] = h;
    ((bf16x4*)lo)[i] = l;
}

// ---------------------------------------------------------------------------
// Split-bf16 MFMA GEMM v2: fragment-order LDS + global_load_lds(16B).
// C[m,n] = sum_k (Ah+Al)[m,k]*(Wh+Wl)[n,k] + bias[n]  (drops Al*Wl, ~2^-16).
// 128x128 tile, BK=32, 4 waves 2x2, wave = 64x64 via 4x4 frags of 16x16x32.
// LDS per matrix = 8 frags x 1KB, frag f = rows 16f..16f+15, k 0..31, stored
// in exact MFMA lane order -> conflict-free ds_read_b128 at base+lane*16.
// ---------------------------------------------------------------------------
__global__ __launch_bounds__(256, 3) void gemm_mfma_v2(
    const ushort* __restrict__ Ah, const ushort* __restrict__ Al,
    const ushort* __restrict__ Wh, const ushort* __restrict__ Wl,
    const float* __restrict__ bias, float* __restrict__ C,
    int M, int N, int K)
{
    __shared__ ushort AhB[8 * 512], AlB[8 * 512], WhB[8 * 512], WlB[8 * 512];

    const int tid = threadIdx.x;
    const int lane = tid & 63;
    const int wv = tid >> 6;
    const int l15 = lane & 15;
    const int quad = lane >> 4;
    const int bm = blockIdx.y * 128;
    const int bn = blockIdx.x * 128;
    const int mw = (wv & 1) * 64;
    const int nw = (wv >> 1) * 64;
    const int mf0 = mw >> 4;  // 0 or 4: first A-frag this wave consumes
    const int nf0 = nw >> 4;

    // staging: wave wv stages frags {2wv, 2wv+1} of each matrix
    const int f0 = wv * 2;
    const ushort* gA0 = Ah + (size_t)(bm + f0 * 16 + l15) * K + quad * 8;
    const ushort* gA1 = Ah + (size_t)(bm + f0 * 16 + 16 + l15) * K + quad * 8;
    const ushort* gAl0 = Al + (size_t)(bm + f0 * 16 + l15) * K + quad * 8;
    const ushort* gAl1 = Al + (size_t)(bm + f0 * 16 + 16 + l15) * K + quad * 8;
    const ushort* gW0 = Wh + (size_t)(bn + f0 * 16 + l15) * K + quad * 8;
    const ushort* gW1 = Wh + (size_t)(bn + f0 * 16 + 16 + l15) * K + quad * 8;
    const ushort* gWl0 = Wl + (size_t)(bn + f0 * 16 + l15) * K + quad * 8;
    const ushort* gWl1 = Wl + (size_t)(bn + f0 * 16 + 16 + l15) * K + quad * 8;

    floatx4 acc[4][4];
#pragma unroll
    for (int i = 0; i < 4; ++i)
#pragma unroll
        for (int j = 0; j < 4; ++j) acc[i][j] = (floatx4){0.f, 0.f, 0.f, 0.f};

    for (int k0 = 0; k0 < K; k0 += 32) {
        g2l16(gA0 + k0, AhB + (f0 + 0) * 512);
        g2l16(gA1 + k0, AhB + (f0 + 1) * 512);
        g2l16(gAl0 + k0, AlB + (f0 + 0) * 512);
        g2l16(gAl1 + k0, AlB + (f0 + 1) * 512);
        g2l16(gW0 + k0, WhB + (f0 + 0) * 512);
        g2l16(gW1 + k0, WhB + (f0 + 1) * 512);
        g2l16(gWl0 + k0, WlB + (f0 + 0) * 512);
        g2l16(gWl1 + k0, WlB + (f0 + 1) * 512);
        __syncthreads();  // vmcnt(0) drain + all waves' stages visible

        bf16x8 aH[4], aL[4], bH[4], bL[4];
#pragma unroll
        for (int f = 0; f < 4; ++f) {
            aH[f] = *(const bf16x8*)(AhB + (mf0 + f) * 512 + lane * 8);
            aL[f] = *(const bf16x8*)(AlB + (mf0 + f) * 512 + lane * 8);
            bH[f] = *(const bf16x8*)(WhB + (nf0 + f) * 512 + lane * 8);
            bL[f] = *(const bf16x8*)(WlB + (nf0 + f) * 512 + lane * 8);
        }
#pragma unroll
        for (int mf = 0; mf < 4; ++mf)
#pragma unroll
            for (int nf = 0; nf < 4; ++nf) {
                acc[mf][nf] = MFMA_BF16(aH[mf], bH[nf], acc[mf][nf]);
                acc[mf][nf] = MFMA_BF16(aH[mf], bL[nf], acc[mf][nf]);
                acc[mf][nf] = MFMA_BF16(aL[mf], bH[nf], acc[mf][nf]);
            }
        __syncthreads();  // LDS consumed before next overwrite
    }

#pragma unroll
    for (int mf = 0; mf < 4; ++mf)
#pragma unroll
        for (int nf = 0; nf < 4; ++nf) {
            int col = bn + nw + nf * 16 + l15;
            float bv = bias[col];
#pragma unroll
            for (int reg = 0; reg < 4; ++reg) {
                int row = bm + mw + mf * 16 + quad * 4 + reg;
                C[(size_t)row * N + col] = acc[mf][nf][reg] + bv;
            }
        }
}

// ---------------------------------------------------------------------------
// rope + head split + bf16 hi/lo split (q pre-scaled by 0.125), v transposed.
// ---------------------------------------------------------------------------
__global__ __launch_bounds__(256) void rope_split_bf16(
    const float* __restrict__ qkv, const float* __restrict__ sp,
    ushort* __restrict__ q_hi, ushort* __restrict__ q_lo,
    ushort* __restrict__ k_hi, ushort* __restrict__ k_lo,
    ushort* __restrict__ v_t)
{
    __shared__ ushort VT[64][72];
    const int s0 = blockIdx.x * 64;
    const int h = blockIdx.y;
    const int b = blockIdx.z;
    const int d = threadIdx.x & 63;
    const int sw = threadIdx.x >> 6;
    const float sgn = (d < 32) ? -1.f : 1.f;

#pragma unroll 4
    for (int i = 0; i < 16; ++i) {
        int sl = i * 4 + sw;
        int s = s0 + sl;
        size_t base = ((size_t)(b * S_ + s)) * (3 * D_) + h * (3 * HD_) + d;
        float tq = qkv[base];
        float tk = qkv[base + HD_];
        float tv = qkv[base + 2 * HD_];
        float spv = sp[s * HD_ + d];
        float c = cosf(spv), sn = sinf(spv);
        float pq = __shfl_xor(tq, 32);
        float pk = __shfl_xor(tk, 32);
        float qv = (tq * c + sgn * pq * sn) * 0.125f;
        float kv = tk * c + sgn * pk * sn;

        size_t o = ((size_t)((b * H_ + h) * S_ + s)) * HD_ + d;
        ushort qh = f2bf(qv);
        q_hi[o] = qh; q_lo[o] = f2bf(qv - bf2f(qh));
        ushort kh = f2bf(kv);
        k_hi[o] = kh; k_lo[o] = f2bf(kv - bf2f(kh));
        VT[d][sl] = f2bf(tv);
    }
    __syncthreads();
    const int dd = threadIdx.x >> 2;
    const int c0 = (threadIdx.x & 3) * 16;
    size_t ob = ((size_t)((b * H_ + h) * HD_ + dd)) * S_ + s0 + c0;
    *(bf16x8*)(v_t + ob)     = *(const bf16x8*)&VT[dd][c0];
    *(bf16x8*)(v_t + ob + 8) = *(const bf16x8*)&VT[dd][c0 + 8];
}

// ---------------------------------------------------------------------------
// MFMA flash attention v4 = v3 + batch-pairing swizzle:
// blockIdx.x = b*32 + q-tile; the (b=0,b=1) pair differ by 32 (same XCD under
// %8 round-robin) and read identical pb/mask slices -> L2/L3 hit for 2nd.
// ---------------------------------------------------------------------------
__global__ __launch_bounds__(256, 3) void attn_flash_v4(
    const ushort* __restrict__ q_hi, const ushort* __restrict__ q_lo,
    const ushort* __restrict__ k_hi, const ushort* __restrict__ k_lo,
    const ushort* __restrict__ v_t, const float* __restrict__ pb,
    const int* __restrict__ mask,
    ushort* __restrict__ vals_hi, ushort* __restrict__ vals_lo)
{
    __shared__ ushort Kh[64][72];
    __shared__ ushort Kl[64][72];
    __shared__ ushort Vt[64][72];
    __shared__ ushort PBM[64][76];
    __shared__ ushort Ps[4][16][72];

    const int tid = threadIdx.x;
    const int lane = tid & 63;
    const int wv = tid >> 6;
    const int l15 = lane & 15;
    const int quad = lane >> 4;
    const int b = blockIdx.x >> 5;
    const int q0 = (blockIdx.x & 31) * 64;
    const int h = blockIdx.y;
    const int qbase = q0 + wv * 16;

    const size_t bh_sd = ((size_t)(b * H_ + h)) * (size_t)S_ * HD_;

    const ushort* qrow_h = q_hi + bh_sd + (size_t)(qbase + l15) * HD_;
    const ushort* qrow_l = q_lo + bh_sd + (size_t)(qbase + l15) * HD_;
    bf16x8 qA_h0 = *(const bf16x8*)(qrow_h + quad * 8);
    bf16x8 qA_h1 = *(const bf16x8*)(qrow_h + 32 + quad * 8);
    bf16x8 qA_l0 = *(const bf16x8*)(qrow_l + quad * 8);
    bf16x8 qA_l1 = *(const bf16x8*)(qrow_l + 32 + quad * 8);

    floatx4 O4[4];
    float l_[4];
#pragma unroll
    for (int f = 0; f < 4; ++f) O4[f] = (floatx4){0.f, 0.f, 0.f, 0.f};
#pragma unroll
    for (int r = 0; r < 4; ++r) l_[r] = 0.f;

    const int kr = tid >> 3;
    const int kc8 = (tid & 7) * 8;
    const int pr = tid >> 4;
    const int pc4 = (tid & 15) * 4;

    bf16x8 pKh[2], pKl[2], pVt[2];
    float4 pPb[4];
    int4 pMk[4];
    auto fetch = [&](int kt) {
#pragma unroll
        for (int u = 0; u < 2; ++u) {
            int r = kr + u * 32;
            pKh[u] = *(const bf16x8*)(k_hi + bh_sd + (size_t)(kt + r) * HD_ + kc8);
            pKl[u] = *(const bf16x8*)(k_lo + bh_sd + (size_t)(kt + r) * HD_ + kc8);
            pVt[u] = *(const bf16x8*)(v_t + bh_sd + (size_t)r * S_ + kt + kc8);
        }
#pragma unroll
        for (int u = 0; u < 4; ++u) {
            int r = pr + u * 16;
            pPb[u] = *(const float4*)(pb + ((size_t)h * S_ + q0 + r) * S_ + kt + pc4);
            pMk[u] = *(const int4*)(mask + (size_t)(q0 + r) * S_ + kt + pc4);
        }
    };

    fetch(0);
    for (int kt = 0; kt < S_; kt += 64) {
        __syncthreads();
#pragma unroll
        for (int u = 0; u < 2; ++u) {
            int r = kr + u * 32;
            *(bf16x8*)&Kh[r][kc8] = pKh[u];
            *(bf16x8*)&Kl[r][kc8] = pKl[u];
            *(bf16x8*)&Vt[r][kc8] = pVt[u];
        }
#pragma unroll
        for (int u = 0; u < 4; ++u) {
            int r = pr + u * 16;
            bf16x4 w;
            w[0] = (short)f2bf(pMk[u].x == 0 ? -9e15f : pPb[u].x * 0.125f);
            w[1] = (short)f2bf(pMk[u].y == 0 ? -9e15f : pPb[u].y * 0.125f);
            w[2] = (short)f2bf(pMk[u].z == 0 ? -9e15f : pPb[u].z * 0.125f);
            w[3] = (short)f2bf(pMk[u].w == 0 ? -9e15f : pPb[u].w * 0.125f);
            *(bf16x4*)&PBM[r][pc4] = w;
        }
        __syncthreads();
        if (kt + 64 < S_) fetch(kt + 64);

        // ---- QK^T, split-bf16
        floatx4 S4[4];
#pragma unroll
        for (int nf = 0; nf < 4; ++nf) {
            const int krow = nf * 16 + l15;
            bf16x8 bh0 = *(const bf16x8*)&Kh[krow][quad * 8];
            bf16x8 bh1 = *(const bf16x8*)&Kh[krow][32 + quad * 8];
            bf16x8 bl0 = *(const bf16x8*)&Kl[krow][quad * 8];
            bf16x8 bl1 = *(const bf16x8*)&Kl[krow][32 + quad * 8];
            floatx4 a = (floatx4){0.f, 0.f, 0.f, 0.f};
            a = MFMA_BF16(qA_h0, bh0, a);
            a = MFMA_BF16(qA_h1, bh1, a);
            a = MFMA_BF16(qA_h0, bl0, a);
            a = MFMA_BF16(qA_h1, bl1, a);
            a = MFMA_BF16(qA_l0, bh0, a);
            a = MFMA_BF16(qA_l1, bh1, a);
            S4[nf] = a;
        }

        // ---- p = exp(S + pbm); per-lane partial l; stash P (A-layout via LDS)
#pragma unroll
        for (int nf = 0; nf < 4; ++nf) {
#pragma unroll
            for (int reg = 0; reg < 4; ++reg) {
                float x = S4[nf][reg] +
                    bf2f(PBM[wv * 16 + quad * 4 + reg][nf * 16 + l15]);
                float p = __expf(x);
                l_[reg] += p;
                Ps[wv][quad * 4 + reg][nf * 16 + l15] = f2bf(p);
            }
        }

        // ---- PV
        bf16x8 pA0 = *(const bf16x8*)&Ps[wv][l15][quad * 8];
        bf16x8 pA1 = *(const bf16x8*)&Ps[wv][l15][32 + quad * 8];
#pragma unroll
        for (int df = 0; df < 4; ++df) {
            const int vrow = df * 16 + l15;
            bf16x8 vB0 = *(const bf16x8*)&Vt[vrow][quad * 8];
            bf16x8 vB1 = *(const bf16x8*)&Vt[vrow][32 + quad * 8];
            O4[df] = MFMA_BF16(pA0, vB0, O4[df]);
            O4[df] = MFMA_BF16(pA1, vB1, O4[df]);
        }
    }

    // ---- epilogue: reduce l across row group, write hi/lo vals
#pragma unroll
    for (int reg = 0; reg < 4; ++reg) {
        float lv = l_[reg];
        lv += __shfl_xor(lv, 1);
        lv += __shfl_xor(lv, 2);
        lv += __shfl_xor(lv, 4);
        lv += __shfl_xor(lv, 8);
        float inv = 1.f / lv;
        const int row = qbase + quad * 4 + reg;
        size_t ob = ((size_t)(b * S_ + row)) * D_ + h * HD_;
#pragma unroll
        for (int df = 0; df < 4; ++df) {
            float o = O4[df][reg] * inv;
            ushort hb = f2bf(o);
            vals_hi[ob + df * 16 + l15] = hb;
            vals_lo[ob + df * 16 + l15] = f2bf(o - bf2f(hb));
        }
    }
}

// ---------------------------------------------------------------------------
extern "C" void kernel_launch(void* const* d_in, const int* in_sizes, int n_in,
                              void* d_out, int out_size, void* d_ws, size_t ws_size,
                              hipStream_t stream) {
    const float* x      = (const float*)d_in[0];
    const float* pos_b  = (const float*)d_in[1];
    const float* sp     = (const float*)d_in[2];
    const int*   mask   = (const int*)d_in[3];
    const float* W_qkv  = (const float*)d_in[4];
    const float* b_qkv  = (const float*)d_in[5];
    const float* W_o    = (const float*)d_in[6];
    const float* b_o    = (const float*)d_in[7];
    float* out = (float*)d_out;

    char* w = (char*)d_ws;
    float*  qkv   = (float*)w;   w += (size_t)4096 * 3072 * 4;   // 48 MB
    ushort* xv_hi = (ushort*)w;  w += (size_t)4096 * 1024 * 2;   // x_hi, later vals_hi
    ushort* xv_lo = (ushort*)w;  w += (size_t)4096 * 1024 * 2;
    ushort* wq_hi = (ushort*)w;  w += (size_t)3072 * 1024 * 2;
    ushort* wq_lo = (ushort*)w;  w += (size_t)3072 * 1024 * 2;
    ushort* wo_hi = (ushort*)w;  w += (size_t)1024 * 1024 * 2;
    ushort* wo_lo = (ushort*)w;  w += (size_t)1024 * 1024 * 2;
    ushort* q_hi  = (ushort*)w;  w += (size_t)B_ * H_ * S_ * HD_ * 2;
    ushort* q_lo  = (ushort*)w;  w += (size_t)B_ * H_ * S_ * HD_ * 2;
    ushort* k_hi  = (ushort*)w;  w += (size_t)B_ * H_ * S_ * HD_ * 2;
    ushort* k_lo  = (ushort*)w;  w += (size_t)B_ * H_ * S_ * HD_ * 2;
    ushort* v_t   = (ushort*)w;  w += (size_t)B_ * H_ * S_ * HD_ * 2;

    f32_split_bf16<<<4096, 256, 0, stream>>>(x, xv_hi, xv_lo, 4096 * 1024 / 4);
    f32_split_bf16<<<3072, 256, 0, stream>>>(W_qkv, wq_hi, wq_lo, 3072 * 1024 / 4);
    f32_split_bf16<<<1024, 256, 0, stream>>>(W_o, wo_hi, wo_lo, 1024 * 1024 / 4);

    gemm_mfma_v2<<<dim3(3072 / 128, 4096 / 128), 256, 0, stream>>>(
        xv_hi, xv_lo, wq_hi, wq_lo, b_qkv, qkv, 4096, 3072, 1024);

    rope_split_bf16<<<dim3(S_ / 64, H_, B_), 256, 0, stream>>>(
        qkv, sp, q_hi, q_lo, k_hi, k_lo, v_t);

    // vals (hi/lo) overwrite the x split buffers (x fully consumed by gemm1)
    attn_flash_v4<<<dim3(2 * (S_ / 64), H_), 256, 0, stream>>>(
        q_hi, q_lo, k_hi, k_lo, v_t, pos_b, mask, xv_hi, xv_lo);

    gemm_mfma_v2<<<dim3(1024 / 128, 4096 / 128), 256, 0, stream>>>(
        xv_hi, xv_lo, wo_hi, wo_lo, b_o, out, 4096, 1024, 1024);
}